// Round 1
// baseline (97.423 us; speedup 1.0000x reference)
//
#include <hip/hip_runtime.h>
#include <hip/hip_bf16.h>

typedef __attribute__((ext_vector_type(8))) short short8_t;
typedef __attribute__((ext_vector_type(4))) float f32x4;

#define BATCH 16
#define CIN   512
#define COUT  512
#define TT    4096

__device__ __forceinline__ ushort f2bf(float f) {
    __hip_bfloat16 h = __float2bfloat16(f);   // RNE; compiler pairs into v_cvt_pk_bf16_f32
    return __builtin_bit_cast(ushort, h);
}

// LDS layout (per tile): k-major granules.
//   LA[kkq][ m ^ (kkq&7) ][8k]          (kkq = kk>>3, plane = 1024 ushorts)
//   LB[kkq][ n ^ ((n>>3)&7) ][8k]
// Fragment read = one ds_read_b128 of 8 contiguous k per lane; perm spreads banks.

extern "C" __global__ __launch_bounds__(256, 2)
void conv2x1_gemm(const float* __restrict__ pre, const float* __restrict__ W,
                  const float* __restrict__ bias, float* __restrict__ out)
{
    __shared__ ushort LA[8 * 1024];   // 16 KiB: 128 m x 64 k bf16
    __shared__ ushort LB[8 * 1024];   // 16 KiB: 64 k x 128 n bf16

    const int tid  = threadIdx.x;
    const int lane = tid & 63;
    const int wv   = tid >> 6;
    const int wm   = wv >> 1, wn = wv & 1;
    const int g    = lane >> 4;
    const int l15  = lane & 15;

    // XCD-chunked swizzle: 2048 blocks, 8 XCDs; consecutive ids (sharing a B-panel
    // across the 4 m-tiles) land on the same XCD's L2.
    const int id   = ((blockIdx.x & 7) << 8) | (blockIdx.x >> 3);
    const int mblk = id & 3;
    const int ti   = (id >> 2) & 31;
    const int bb   = id >> 7;

    const int m0 = mblk << 7;
    const int t0 = ti << 7;

    const float* preB = pre + (size_t)bb * ((size_t)CIN * TT);

    // staging coords (constant across K-tiles)
    const int a_m  = tid >> 4;   // + it*16 ; A: 8 iters of dwordx4 (4 k each)
    const int a_kq = tid & 15;
    const int b_kk = tid >> 6;   // + it*4  ; B: 16 iters of dwordx2 (2 t each)
    const int b_h  = tid & 63;

    uint a_pk[8][2];
    uint b_pk[16];

    f32x4 acc[4][4];
#pragma unroll
    for (int i = 0; i < 4; ++i)
#pragma unroll
        for (int j = 0; j < 4; ++j) acc[i][j] = (f32x4)0.0f;

#define LOAD_A(KT) do { \
    _Pragma("unroll") \
    for (int it = 0; it < 8; ++it) { \
        const float4 v = *(const float4*)(W + (size_t)(m0 + it*16 + a_m) * CIN + (KT)*64 + a_kq*4); \
        a_pk[it][0] = (uint)f2bf(v.x) | ((uint)f2bf(v.y) << 16); \
        a_pk[it][1] = (uint)f2bf(v.z) | ((uint)f2bf(v.w) << 16); \
    } } while (0)

#define LOAD_B(KT) do { \
    _Pragma("unroll") \
    for (int it = 0; it < 16; ++it) { \
        const float2 v = *(const float2*)(preB + (size_t)((KT)*64 + it*4 + b_kk) * TT + t0 + b_h*2); \
        b_pk[it] = (uint)f2bf(v.x) | ((uint)f2bf(v.y) << 16); \
    } } while (0)

#define WRITE_A() do { \
    _Pragma("unroll") \
    for (int it = 0; it < 8; ++it) { \
        const int m   = it*16 + a_m; \
        const int kkq = a_kq >> 1; \
        const int k7  = (a_kq & 1) << 2; \
        const int idx = (kkq << 10) + ((m ^ (kkq & 7)) << 3) + k7; \
        *(uint2*)&LA[idx] = make_uint2(a_pk[it][0], a_pk[it][1]); \
    } } while (0)

#define WRITE_B() do { \
    _Pragma("unroll") \
    for (int it = 0; it < 16; ++it) { \
        const int kk  = it*4 + b_kk; \
        const int kkq = kk >> 3, k7 = kk & 7; \
        const int n   = b_h * 2; \
        LB[(kkq << 10) + ((n       ^ ((n     >> 3) & 7)) << 3) + k7] = (ushort)(b_pk[it]); \
        LB[(kkq << 10) + (((n + 1) ^ (((n+1) >> 3) & 7)) << 3) + k7] = (ushort)(b_pk[it] >> 16); \
    } } while (0)

#define COMPUTE() do { \
    _Pragma("unroll") \
    for (int ks = 0; ks < 2; ++ks) { \
        const int kkq = ks*4 + g; \
        short8_t af[4], bfr[4]; \
        _Pragma("unroll") \
        for (int mi = 0; mi < 4; ++mi) { \
            const int m = wm*64 + mi*16 + l15; \
            af[mi] = *(const short8_t*)&LA[(kkq << 10) + ((m ^ (kkq & 7)) << 3)]; \
        } \
        _Pragma("unroll") \
        for (int ni = 0; ni < 4; ++ni) { \
            const int n = wn*64 + ni*16 + l15; \
            bfr[ni] = *(const short8_t*)&LB[(kkq << 10) + ((n ^ ((n >> 3) & 7)) << 3)]; \
        } \
        _Pragma("unroll") \
        for (int mi = 0; mi < 4; ++mi) \
            _Pragma("unroll") \
            for (int ni = 0; ni < 4; ++ni) \
                acc[mi][ni] = __builtin_amdgcn_mfma_f32_16x16x32_bf16(af[mi], bfr[ni], acc[mi][ni], 0, 0, 0); \
    } } while (0)

    LOAD_A(0);
    LOAD_B(0);

    for (int kt = 0; kt < 8; ++kt) {
        __syncthreads();            // previous iteration's LDS reads complete
        WRITE_A();
        WRITE_B();
        __syncthreads();            // tile visible
        if (kt < 7) {               // issue next-tile global loads early (hide under MFMA)
            LOAD_A(kt + 1);
            LOAD_B(kt + 1);
        }
        COMPUTE();
    }

    // epilogue: out = 2*(acc + bias)
    const int orow = m0 + wm*64 + g*4;     // + mi*16 + r
    float bv[4][4];
#pragma unroll
    for (int mi = 0; mi < 4; ++mi)
#pragma unroll
        for (int r = 0; r < 4; ++r)
            bv[mi][r] = bias[orow + mi*16 + r];

    float* outB = out + (size_t)bb * ((size_t)COUT * TT);
#pragma unroll
    for (int mi = 0; mi < 4; ++mi) {
#pragma unroll
        for (int ni = 0; ni < 4; ++ni) {
            const int t = t0 + wn*64 + ni*16 + l15;
#pragma unroll
            for (int r = 0; r < 4; ++r) {
                const int o = orow + mi*16 + r;
                outB[(size_t)o * TT + t] = 2.0f * (acc[mi][ni][r] + bv[mi][r]);
            }
        }
    }
}

extern "C" void kernel_launch(void* const* d_in, const int* in_sizes, int n_in,
                              void* d_out, int out_size, void* d_ws, size_t ws_size,
                              hipStream_t stream)
{
    const float* pre  = (const float*)d_in[0];   // [16, 512, 4096] fp32
    const float* Wp   = (const float*)d_in[1];   // [512, 512] fp32
    const float* bias = (const float*)d_in[2];   // [512] fp32
    float* out = (float*)d_out;                  // [16, 512, 4096] fp32

    dim3 grid(BATCH * 4 * 32);   // 16 batches x 4 m-tiles x 32 t-tiles = 2048
    dim3 block(256);
    hipLaunchKernelGGL(conv2x1_gemm, grid, block, 0, stream, pre, Wp, bias, out);
}